// Round 1
// baseline (2068.510 us; speedup 1.0000x reference)
//
#include <hip/hip_runtime.h>
#include <hip/hip_bf16.h>
#include <math.h>

// Problem constants (B,T,C,H) = (4, 2048, 1024, 16), D = 64.
#define B_   4
#define T_   2048
#define C_   1024
#define H_   16
#define D_   64
#define TC3  3072   // 3*C

// ---------------------------------------------------------------------------
// GEMM: C[M,N] = A[M,K] @ Bm[K,N] + bias[N]
// A has leading dim lda (lets GEMM2 read the attn result strided out of the
// qkv workspace). Bm/C are dense (ldb = ldc = N).
// 128x128 block tile, BK=8, 256 threads, 8x8 micro-tile per thread.
// All of M, N, K here are multiples of the tile sizes -> no bounds checks.
// ---------------------------------------------------------------------------
__global__ __launch_bounds__(256)
void sgemm_bias(const float* __restrict__ A, const float* __restrict__ Bm,
                const float* __restrict__ bias, float* __restrict__ Cm,
                int M, int N, int K, int lda) {
  __shared__ __align__(16) float As[8][128];   // transposed: As[k][m]
  __shared__ __align__(16) float Bs[8][128];

  const int tid  = threadIdx.x;
  const int tr   = tid >> 4;          // 0..15  (row group)
  const int tc   = tid & 15;          // 0..15  (col group)
  const int row0 = blockIdx.y * 128;
  const int col0 = blockIdx.x * 128;

  const int arow = tid >> 1;          // 0..127
  const int acol = (tid & 1) * 4;     // 0 or 4
  const int brow = tid >> 5;          // 0..7
  const int bcol = (tid & 31) * 4;    // 0..124

  const float* Aptr = A  + (size_t)(row0 + arow) * lda + acol;
  const float* Bptr = Bm + (size_t)brow * N + col0 + bcol;

  float acc[8][8];
#pragma unroll
  for (int i = 0; i < 8; ++i)
#pragma unroll
    for (int j = 0; j < 8; ++j) acc[i][j] = 0.f;

  for (int kt = 0; kt < K; kt += 8) {
    float4 av = *(const float4*)(Aptr + kt);
    float4 bv = *(const float4*)(Bptr + (size_t)kt * N);
    As[acol + 0][arow] = av.x;
    As[acol + 1][arow] = av.y;
    As[acol + 2][arow] = av.z;
    As[acol + 3][arow] = av.w;
    *(float4*)&Bs[brow][bcol] = bv;
    __syncthreads();

#pragma unroll
    for (int k = 0; k < 8; ++k) {
      float4 a0 = *(const float4*)&As[k][tr * 8];
      float4 a1 = *(const float4*)&As[k][tr * 8 + 4];
      float4 b0 = *(const float4*)&Bs[k][tc * 8];
      float4 b1 = *(const float4*)&Bs[k][tc * 8 + 4];
      float af[8] = {a0.x, a0.y, a0.z, a0.w, a1.x, a1.y, a1.z, a1.w};
      float bf[8] = {b0.x, b0.y, b0.z, b0.w, b1.x, b1.y, b1.z, b1.w};
#pragma unroll
      for (int i = 0; i < 8; ++i)
#pragma unroll
        for (int j = 0; j < 8; ++j)
          acc[i][j] = fmaf(af[i], bf[j], acc[i][j]);
    }
    __syncthreads();
  }

  // epilogue: add bias, float4 stores
  float4 bs0 = *(const float4*)&bias[col0 + tc * 8];
  float4 bs1 = *(const float4*)&bias[col0 + tc * 8 + 4];
  float bf[8] = {bs0.x, bs0.y, bs0.z, bs0.w, bs1.x, bs1.y, bs1.z, bs1.w};
#pragma unroll
  for (int i = 0; i < 8; ++i) {
    size_t r = (size_t)(row0 + tr * 8 + i) * N + col0 + tc * 8;
    float4 o0 = {acc[i][0] + bf[0], acc[i][1] + bf[1],
                 acc[i][2] + bf[2], acc[i][3] + bf[3]};
    float4 o1 = {acc[i][4] + bf[4], acc[i][5] + bf[5],
                 acc[i][6] + bf[6], acc[i][7] + bf[7]};
    *(float4*)&Cm[r]     = o0;
    *(float4*)&Cm[r + 4] = o1;
  }
}

// ---------------------------------------------------------------------------
// Fused per-head RMSNorm + RoPE (in-place on q,k inside qkv) and the value
// output ((1-lamb)*v + lamb*v) written in (B,H,T,D) layout.
// One wave (64 lanes) per (b,t,h); D = 64 = wave width, lane = d.
// Rotate-half partner for lane d is lane d^32.
// ---------------------------------------------------------------------------
__global__ __launch_bounds__(256)
void rmsrope_kernel(float* __restrict__ qkv, const float* __restrict__ lambp,
                    float* __restrict__ valOut) {
  const int unit = blockIdx.x * 4 + (threadIdx.x >> 6);   // (b,t,h) id
  const int lane = threadIdx.x & 63;                      // = d
  const int b = unit / (T_ * H_);
  const int rem = unit % (T_ * H_);
  const int t = rem / H_;
  const int h = rem % H_;
  const size_t base = (size_t)(b * T_ + t) * TC3;
  const float lamb = lambp[0];

  // RoPE table entry (matches reference fp32 math):
  // inv_freq[i] = 1 / 10000^(2i/64), freqs = t * inv_freq
  const int i = lane & 31;
  const float inv = 1.0f / powf(10000.0f, (float)(2 * i) * (1.0f / 64.0f));
  const float ang = (float)t * inv;
  const float cs = cosf(ang);
  const float sn = sinf(ang);

  // ---- q ----
  {
    const size_t idx = base + h * 64 + lane;
    float q = qkv[idx];
    float ss = q * q;
    ss += __shfl_xor(ss, 32); ss += __shfl_xor(ss, 16);
    ss += __shfl_xor(ss, 8);  ss += __shfl_xor(ss, 4);
    ss += __shfl_xor(ss, 2);  ss += __shfl_xor(ss, 1);
    float qn = q * (1.0f / sqrtf(ss * (1.0f / 64.0f) + 1e-6f));
    float part = __shfl_xor(qn, 32);
    // lane<32: x1*cos + x2*sin ; lane>=32: -x1*sin + x2*cos
    float out = (lane < 32) ? (qn * cs + part * sn) : (qn * cs - part * sn);
    qkv[idx] = out;
  }
  // ---- k ----
  {
    const size_t idx = base + C_ + h * 64 + lane;
    float k = qkv[idx];
    float ss = k * k;
    ss += __shfl_xor(ss, 32); ss += __shfl_xor(ss, 16);
    ss += __shfl_xor(ss, 8);  ss += __shfl_xor(ss, 4);
    ss += __shfl_xor(ss, 2);  ss += __shfl_xor(ss, 1);
    float kn = k * (1.0f / sqrtf(ss * (1.0f / 64.0f) + 1e-6f));
    float part = __shfl_xor(kn, 32);
    float out = (lane < 32) ? (kn * cs + part * sn) : (kn * cs - part * sn);
    qkv[idx] = out;
  }
  // ---- value output (second tuple element), (B,H,T,D) layout ----
  {
    float v = qkv[base + 2 * C_ + h * 64 + lane];
    float val = (1.0f - lamb) * v + lamb * v;
    valOut[(size_t)((b * H_ + h) * T_ + t) * D_ + lane] = val;
  }
}

// ---------------------------------------------------------------------------
// Flash-style causal attention, fp32.
// Block = 256 threads handles one (b, h, 64-row Q tile); iterates 64-key
// tiles with online softmax. 4x4 register micro-tile per thread.
// LDS tiles use stride 68 floats (272 B: 16B-aligned rows, <=2-way bank
// aliasing on all hot-loop float4 reads). P^T aliases the K tile so static
// LDS stays at 52.2 KB (3 blocks/CU).
// Output O/l is written into the (dead) v-columns of the qkv workspace in
// (b, t, h*64+d) layout, which is exactly the GEMM2 A operand (lda=3072).
// ---------------------------------------------------------------------------
__global__ __launch_bounds__(256)
void flash_kernel(float* __restrict__ qkv, const float* __restrict__ vvals) {
  __shared__ __align__(16) float Qs[64][68];
  __shared__ __align__(16) float Ks[64][68];
  __shared__ __align__(16) float Vs[64][68];
  float* Ps = &Ks[0][0];   // P^T overwrites K tile after S-compute

  const int qt = blockIdx.x;
  const int h  = blockIdx.y;
  const int b  = blockIdx.z;
  const int tid = threadIdx.x;
  const int ty = tid >> 4;          // 0..15 -> rows 4*ty..4*ty+3
  const int tx = tid & 15;          // 0..15 -> cols 4*tx..4*tx+3
  const int q0 = qt * 64;
  const int lrow = tid >> 4;        // load mapping
  const int lcol = (tid & 15) * 4;

  // Q tile -> LDS
#pragma unroll
  for (int it = 0; it < 4; ++it) {
    int r = it * 16 + lrow;
    *(float4*)&Qs[r][lcol] =
        *(const float4*)(qkv + (size_t)(b * T_ + q0 + r) * TC3 + h * 64 + lcol);
  }

  float m_i[4], l_i[4], o[4][4];
#pragma unroll
  for (int ii = 0; ii < 4; ++ii) {
    m_i[ii] = -INFINITY; l_i[ii] = 0.f;
#pragma unroll
    for (int dd = 0; dd < 4; ++dd) o[ii][dd] = 0.f;
  }

  for (int kt = 0; kt <= qt; ++kt) {
    const int k0 = kt * 64;
    __syncthreads();   // previous P^T / V fully consumed
#pragma unroll
    for (int it = 0; it < 4; ++it) {
      int r = it * 16 + lrow;
      *(float4*)&Ks[r][lcol] = *(const float4*)(
          qkv + (size_t)(b * T_ + k0 + r) * TC3 + C_ + h * 64 + lcol);
      *(float4*)&Vs[r][lcol] = *(const float4*)(
          vvals + (size_t)((b * H_ + h) * T_ + k0 + r) * D_ + lcol);
    }
    __syncthreads();

    // S = Q K^T  (4x4 per thread, float4 along d)
    float s[4][4];
#pragma unroll
    for (int ii = 0; ii < 4; ++ii)
#pragma unroll
      for (int jj = 0; jj < 4; ++jj) s[ii][jj] = 0.f;

#pragma unroll 4
    for (int d4 = 0; d4 < 16; ++d4) {
      float qa[4][4], ka[4][4];
#pragma unroll
      for (int ii = 0; ii < 4; ++ii) {
        float4 qv = *(const float4*)&Qs[4 * ty + ii][d4 * 4];
        qa[ii][0] = qv.x; qa[ii][1] = qv.y; qa[ii][2] = qv.z; qa[ii][3] = qv.w;
      }
#pragma unroll
      for (int jj = 0; jj < 4; ++jj) {
        float4 kv = *(const float4*)&Ks[4 * tx + jj][d4 * 4];
        ka[jj][0] = kv.x; ka[jj][1] = kv.y; ka[jj][2] = kv.z; ka[jj][3] = kv.w;
      }
#pragma unroll
      for (int ii = 0; ii < 4; ++ii)
#pragma unroll
        for (int jj = 0; jj < 4; ++jj)
#pragma unroll
          for (int c = 0; c < 4; ++c)
            s[ii][jj] = fmaf(qa[ii][c], ka[jj][c], s[ii][jj]);
    }

    // scale + causal mask (only the diagonal tile needs masking)
    const bool diag = (kt == qt);
#pragma unroll
    for (int ii = 0; ii < 4; ++ii)
#pragma unroll
      for (int jj = 0; jj < 4; ++jj) {
        float sv = s[ii][jj] * 0.125f;   // 1/sqrt(64)
        if (diag && (4 * tx + jj > 4 * ty + ii)) sv = -INFINITY;
        s[ii][jj] = sv;
      }

    __syncthreads();   // everyone done reading Ks -> P^T may overwrite it

    // online softmax (row state replicated across the 16 tx threads)
    float p[4][4];
#pragma unroll
    for (int ii = 0; ii < 4; ++ii) {
      float rm = fmaxf(fmaxf(s[ii][0], s[ii][1]), fmaxf(s[ii][2], s[ii][3]));
      rm = fmaxf(rm, __shfl_xor(rm, 1));
      rm = fmaxf(rm, __shfl_xor(rm, 2));
      rm = fmaxf(rm, __shfl_xor(rm, 4));
      rm = fmaxf(rm, __shfl_xor(rm, 8));
      float mnew = fmaxf(m_i[ii], rm);
      float alpha = expf(m_i[ii] - mnew);
      m_i[ii] = mnew;
      float rs = 0.f;
#pragma unroll
      for (int jj = 0; jj < 4; ++jj) {
        p[ii][jj] = expf(s[ii][jj] - mnew);
        rs += p[ii][jj];
      }
      rs += __shfl_xor(rs, 1); rs += __shfl_xor(rs, 2);
      rs += __shfl_xor(rs, 4); rs += __shfl_xor(rs, 8);
      l_i[ii] = l_i[ii] * alpha + rs;
#pragma unroll
      for (int dd = 0; dd < 4; ++dd) o[ii][dd] *= alpha;
    }

    // write P^T (cols->rows) into Ps; one float4 per jj
#pragma unroll
    for (int jj = 0; jj < 4; ++jj) {
      float4 pv = {p[0][jj], p[1][jj], p[2][jj], p[3][jj]};
      *(float4*)&Ps[(size_t)(4 * tx + jj) * 68 + 4 * ty] = pv;
    }
    __syncthreads();

    // O += P V
#pragma unroll 8
    for (int j = 0; j < 64; ++j) {
      float4 pv4 = *(const float4*)&Ps[(size_t)j * 68 + 4 * ty];
      float4 vv4 = *(const float4*)&Vs[j][4 * tx];
      float pa[4] = {pv4.x, pv4.y, pv4.z, pv4.w};
      float va[4] = {vv4.x, vv4.y, vv4.z, vv4.w};
#pragma unroll
      for (int ii = 0; ii < 4; ++ii)
#pragma unroll
        for (int dd = 0; dd < 4; ++dd)
          o[ii][dd] = fmaf(pa[ii], va[dd], o[ii][dd]);
    }
  }

  // epilogue: O/l into qkv's v-columns, (b, t, h*64+d) layout
#pragma unroll
  for (int ii = 0; ii < 4; ++ii) {
    float invl = 1.0f / l_i[ii];
    int row = q0 + 4 * ty + ii;
    float4 ov = {o[ii][0] * invl, o[ii][1] * invl,
                 o[ii][2] * invl, o[ii][3] * invl};
    *(float4*)&qkv[(size_t)(b * T_ + row) * TC3 + 2 * C_ + h * 64 + 4 * tx] = ov;
  }
}

// ---------------------------------------------------------------------------
// Launch. d_in order: x, Wqkv, bqkv, Wproj, bproj, lamb.
// d_out: out (B*T*C floats) then value (B*H*T*D floats).
// Workspace: qkv (B*T*3C floats = 100.7 MB). Attn output reuses the v-columns
// of qkv, so no second scratch buffer is needed.
// ---------------------------------------------------------------------------
extern "C" void kernel_launch(void* const* d_in, const int* in_sizes, int n_in,
                              void* d_out, int out_size, void* d_ws, size_t ws_size,
                              hipStream_t stream) {
  const float* x     = (const float*)d_in[0];
  const float* Wqkv  = (const float*)d_in[1];
  const float* bqkv  = (const float*)d_in[2];
  const float* Wproj = (const float*)d_in[3];
  const float* bproj = (const float*)d_in[4];
  const float* lamb  = (const float*)d_in[5];

  float* out     = (float*)d_out;                       // (B,T,C)
  float* val_out = out + (size_t)B_ * T_ * C_;          // (B,H,T,D)
  float* qkv     = (float*)d_ws;                        // (B,T,3C)

  // 1) qkv = x @ Wqkv + bqkv        (M=8192, N=3072, K=1024)
  sgemm_bias<<<dim3(TC3 / 128, (B_ * T_) / 128), 256, 0, stream>>>(
      x, Wqkv, bqkv, qkv, B_ * T_, TC3, C_, C_);

  // 2) RMSNorm + RoPE in-place on q,k; value -> d_out
  rmsrope_kernel<<<dim3((B_ * T_ * H_) / 4), 256, 0, stream>>>(qkv, lamb, val_out);

  // 3) causal flash attention; result into qkv v-columns
  flash_kernel<<<dim3(T_ / 64, H_, B_), 256, 0, stream>>>(qkv, val_out);

  // 4) out = attn @ Wproj + bproj   (M=8192, N=1024, K=1024, lda=3072)
  sgemm_bias<<<dim3(C_ / 128, (B_ * T_) / 128), 256, 0, stream>>>(
      qkv + 2 * C_, Wproj, bproj, out, B_ * T_, C_, C_, TC3);
}